// Round 13
// baseline (440.320 us; speedup 1.0000x reference)
//
#include <hip/hip_runtime.h>
#include <hip/hip_fp16.h>

#define TOKENS 4096
#define NN 2048
#define IN_DIM 1024
#define OUT_DIM 1024
#define TSTEPS 3

typedef _Float16 half8 __attribute__((ext_vector_type(8)));
typedef _Float16 half4 __attribute__((ext_vector_type(4)));
typedef float f32x4 __attribute__((ext_vector_type(4)));

__device__ __forceinline__ void gload_lds16(const void* g, void* l) {
    __builtin_amdgcn_global_load_lds(
        (const __attribute__((address_space(1))) unsigned*)g,
        (__attribute__((address_space(3))) unsigned*)l, 16, 0, 0);
}

#define LGKM(N) asm volatile("s_waitcnt lgkmcnt(" #N ")" ::: "memory")
#define VMCNT(N) asm volatile("s_waitcnt vmcnt(" #N ")" ::: "memory")
#define SCHED0() __builtin_amdgcn_sched_barrier(0)

// ============ fused dual-GEMM + step (recurrent iteration) ============
// 256 blocks x 512 threads (8 waves). Each block owns a 128x256 output tile
// of BOTH GEMMs: acc1 = state @ effT^T-layout, acc2 = s @ JmT^T-layout
// (wave-tile 64x64 per GEMM, acc = 2 x 64 VGPR). BK=32, LDS 2 x 48KB dbuf.
// r8 counted ledger: 6 stage calls/tile, steady VMCNT(6); per tile
// {issue 16 reads, LGKM(8), MFMA1, LGKM(0), bar, stage T+2, VMCNT, bar,
//  MFMA2 (overlaps next tile's read issue)}. r5's proven 0-conflict swizzle.
// Epilogue: state' = tanh(sig + lam*sj*s_old + noise*Tsc); writes f16
// state'/tanh(state') directly (step_kernel eliminated).
__global__ __launch_bounds__(512, 2)
void fused_dual(const _Float16* __restrict__ stateA, const _Float16* __restrict__ sA,
                const _Float16* __restrict__ effT, const _Float16* __restrict__ JmT,
                const float* __restrict__ noise, const float* __restrict__ Tsc,
                const float* __restrict__ lamp,
                _Float16* __restrict__ stateB, _Float16* __restrict__ sB)
{
    __shared__ __align__(16) _Float16 lds[2 * 24576];   // 96 KiB
    const int tid  = threadIdx.x;
    const int wid  = tid >> 6;
    const int lane = tid & 63;

    // XCD-chunked swizzle: 256 = 8 * 32, bijective
    const int raw  = blockIdx.x;
    const int widx = (raw & 7) * 32 + (raw >> 3);
    const int by = widx >> 3;    // 4096/128 = 32 row tiles
    const int bx = widx & 7;     // 2048/256 = 8 col tiles
    const int brow = by << 7;
    const int bcol = bx << 8;

    // staging: call = 512 thr x 16B = 8KB = 128 rows x 64B (32 f16).
    // thread t: row = t>>2, phys chunk16 = t&3, fetch logical chunk
    // (t&3)^((t>>3)&3) = (t&3)^((row>>1)&3)  (involution).
    const int sr = tid >> 2;
    const int sc = ((tid & 3) ^ ((tid >> 3) & 3)) << 3;
    const _Float16* gSt = stateA + (size_t)(brow + sr) * NN + sc;
    const _Float16* gS  = sA     + (size_t)(brow + sr) * NN + sc;
    const _Float16* gE  = effT   + (size_t)(bcol + sr) * NN + sc;
    const _Float16* gJ  = JmT    + (size_t)(bcol + sr) * NN + sc;
    const int ldst = wid << 9;   // wave slice: 64 thr x 16B = 512 f16

    // buffer layout (f16): state[128][32]@0, s@4096, eff[256][32]@8192, Jm@16384
    auto stage = [&](int T) {     // 6 calls
        _Float16* l = lds + (T & 1) * 24576;
        const int p = T << 5;
        gload_lds16(gSt + p,            l + ldst);
        gload_lds16(gS  + p,            l + 4096  + ldst);
        gload_lds16(gE  + p,            l + 8192  + ldst);
        gload_lds16(gE + 128 * NN + p,  l + 12288 + ldst);
        gload_lds16(gJ  + p,            l + 16384 + ldst);
        gload_lds16(gJ + 128 * NN + p,  l + 20480 + ldst);
    };

    // read geometry: row R -> phys chunk = lq ^ ((R>>1)&3) = lq ^ ((lr>>1)&3)
    const int wr = (wid >> 2) << 6;   // 0 / 64
    const int wc = (wid & 3) << 6;    // 0 / 64 / 128 / 192
    const int lr = lane & 15;
    const int lq = lane >> 4;
    const int swz = (lq ^ ((lr >> 1) & 3)) << 3;
    const int aStR = (wr + lr) * 32 + swz;            // + m*512
    const int aSR  = 4096  + (wr + lr) * 32 + swz;
    const int bER  = 8192  + (wc + lr) * 32 + swz;    // + n*512
    const int bJR  = 16384 + (wc + lr) * 32 + swz;

    f32x4 acc1[4][4], acc2[4][4];
#pragma unroll
    for (int m = 0; m < 4; ++m)
#pragma unroll
        for (int n = 0; n < 4; ++n) {
            acc1[m][n] = (f32x4){0.f, 0.f, 0.f, 0.f};
            acc2[m][n] = (f32x4){0.f, 0.f, 0.f, 0.f};
        }

    half8 a1[4], b1[4], a2[4], b2[4];

    // prologue: stage tiles 0,1 (12 calls); VMCNT(6) proves tile 0 resident
    stage(0); stage(1);
    VMCNT(6);
    __builtin_amdgcn_s_barrier();
    asm volatile("" ::: "memory");

    for (int T = 0; T < 64; ++T) {
        const _Float16* lb = lds + (T & 1) * 24576;

        // ---- issue all 16 reads (GEMM1 first 8, GEMM2 next 8) ----
#pragma unroll
        for (int m = 0; m < 4; ++m) a1[m] = *(const half8*)&lb[aStR + (m << 9)];
#pragma unroll
        for (int n = 0; n < 4; ++n) b1[n] = *(const half8*)&lb[bER + (n << 9)];
#pragma unroll
        for (int m = 0; m < 4; ++m) a2[m] = *(const half8*)&lb[aSR + (m << 9)];
#pragma unroll
        for (int n = 0; n < 4; ++n) b2[n] = *(const half8*)&lb[bJR + (n << 9)];

        // ---- GEMM1 MFMA (gates on its own 8; GEMM2's 8 still in flight) ----
        LGKM(8);
        SCHED0();
        __builtin_amdgcn_s_setprio(1);
#pragma unroll
        for (int m = 0; m < 4; ++m)
#pragma unroll
            for (int n = 0; n < 4; ++n)
                acc1[m][n] = __builtin_amdgcn_mfma_f32_16x16x32_f16(a1[m], b1[n], acc1[m][n], 0, 0, 0);
        __builtin_amdgcn_s_setprio(0);
        SCHED0();

        LGKM(0);   // all 16 retired: this wave done reading tile T
        __builtin_amdgcn_s_barrier();          // #1: ALL waves done with tile T
        if (T < 62) stage(T + 2);              // overwrites buffer (T&1): safe
        if (T < 62) { VMCNT(6); }              // tile T+1 fully resident
        else        { VMCNT(0); }
        __builtin_amdgcn_s_barrier();          // #2: residency visible block-wide
        asm volatile("" ::: "memory");

        // ---- GEMM2 MFMA (registers only; overlaps next tile's read issue) ----
        __builtin_amdgcn_s_setprio(1);
#pragma unroll
        for (int m = 0; m < 4; ++m)
#pragma unroll
            for (int n = 0; n < 4; ++n)
                acc2[m][n] = __builtin_amdgcn_mfma_f32_16x16x32_f16(a2[m], b2[n], acc2[m][n], 0, 0, 0);
        __builtin_amdgcn_s_setprio(0);
        SCHED0();
    }

    // ---- fused step epilogue. C/D layout: col=lane&15, row=(lane>>4)*4+j ----
    const float lam = lamp[0];
    const int cr = lq << 2;
    const int cc = lane & 15;
#pragma unroll
    for (int m = 0; m < 4; ++m) {
#pragma unroll
        for (int n = 0; n < 4; ++n) {
            const int ccol = bcol + wc + n * 16 + cc;
            const float tv = Tsc[ccol];
#pragma unroll
            for (int j = 0; j < 4; ++j) {
                const int crow = brow + wr + m * 16 + cr + j;
                const size_t o = (size_t)crow * NN + ccol;
                float s_old = (float)sA[o];
                float arg = acc1[m][n][j] + lam * (acc2[m][n][j] * s_old)
                          + noise[o] * tv;
                float st = tanhf(arg);
                stateB[o] = (_Float16)st;
                sB[o]     = (_Float16)tanhf(st);
            }
        }
    }
}

// ============ pipelined 128x128 GEMM (input/output projections) ============
// EPI 1: v+=bias; oSta=f16(v); oS=f16(tanh(v)).  EPI 2: Cout=v+bias (f32).
template<int EPI>
__global__ __launch_bounds__(256, 2)
void pgemm(const _Float16* __restrict__ A, const _Float16* __restrict__ B,
           float* __restrict__ Cout, const float* __restrict__ bias,
           _Float16* __restrict__ oSta, _Float16* __restrict__ oS,
           int K, int N, int nbxLog2)
{
    __shared__ __align__(16) _Float16 lds[2 * 16384];   // 64 KiB
    const int tid  = threadIdx.x;
    const int wid  = tid >> 6;
    const int lane = tid & 63;

    const int raw  = blockIdx.x;
    const int cpx  = gridDim.x >> 3;
    const int widx = (raw & 7) * cpx + (raw >> 3);
    const int by = widx >> nbxLog2;
    const int bx = widx & ((1 << nbxLog2) - 1);
    const int brow = by << 7;
    const int bcol = bx << 7;

    const int sr = tid >> 3;
    const int sc = ((tid & 7) ^ (sr & 7)) << 3;
    const _Float16* gA = A + (size_t)(brow + sr) * K + sc;
    const _Float16* gB = B + (size_t)(bcol + sr) * K + sc;
    const int ldst = wid << 9;

    auto stA = [&](int T) {
        _Float16* l = lds + (T & 1) * 16384;
        const _Float16* p = gA + (T << 6);
#pragma unroll
        for (int r = 0; r < 4; ++r)
            gload_lds16(p + (size_t)(r * 32) * K, l + r * 2048 + ldst);
    };
    auto stB = [&](int T) {
        _Float16* l = lds + (T & 1) * 16384 + 8192;
        const _Float16* p = gB + (T << 6);
#pragma unroll
        for (int r = 0; r < 4; ++r)
            gload_lds16(p + (size_t)(r * 32) * K, l + r * 2048 + ldst);
    };

    const int wr = (wid >> 1) << 6;
    const int wc = (wid & 1) << 6;
    const int lr = lane & 15;
    const int lq = lane >> 4;
    const int x7 = lr & 7;
    const int c0 = (lq ^ x7) << 3;
    const int c1 = ((4 + lq) ^ x7) << 3;
    const int aRow = (wr + lr) << 6;
    const int bRow = 8192 + ((wc + lr) << 6);

    f32x4 acc[4][4];
#pragma unroll
    for (int m = 0; m < 4; ++m)
#pragma unroll
        for (int n = 0; n < 4; ++n) acc[m][n] = (f32x4){0.f, 0.f, 0.f, 0.f};

    half8 af0[4], af1[4], bf0[4], bf1[4];
    const int NT = K >> 6;

    stA(0); stB(0); stA(1); stB(1);
    VMCNT(8);
    __builtin_amdgcn_s_barrier();
    {
        const _Float16* lb = lds;
#pragma unroll
        for (int m = 0; m < 4; ++m) af0[m] = *(const half8*)&lb[aRow + (m << 10) + c0];
#pragma unroll
        for (int n = 0; n < 4; ++n) bf0[n] = *(const half8*)&lb[bRow + (n << 10) + c0];
    }

    for (int T = 0; T < NT; ++T) {
        const _Float16* lb = lds + (T & 1) * 16384;

#pragma unroll
        for (int m = 0; m < 4; ++m) af1[m] = *(const half8*)&lb[aRow + (m << 10) + c1];
#pragma unroll
        for (int n = 0; n < 4; ++n) bf1[n] = *(const half8*)&lb[bRow + (n << 10) + c1];
        LGKM(8);
        SCHED0();
        __builtin_amdgcn_s_setprio(1);
#pragma unroll
        for (int m = 0; m < 4; ++m)
#pragma unroll
            for (int n = 0; n < 4; ++n)
                acc[m][n] = __builtin_amdgcn_mfma_f32_16x16x32_f16(af0[m], bf0[n], acc[m][n], 0, 0, 0);
        __builtin_amdgcn_s_setprio(0);
        SCHED0();

        LGKM(0);
        __builtin_amdgcn_s_barrier();
        if (T < NT - 2) { stA(T + 2); stB(T + 2); VMCNT(8); }
        else if (T == NT - 2) { VMCNT(0); }
        __builtin_amdgcn_s_barrier();
        asm volatile("" ::: "memory");

        if (T < NT - 1) {
            const _Float16* ln = lds + ((T + 1) & 1) * 16384;
#pragma unroll
            for (int m = 0; m < 4; ++m) af0[m] = *(const half8*)&ln[aRow + (m << 10) + c0];
#pragma unroll
            for (int n = 0; n < 4; ++n) bf0[n] = *(const half8*)&ln[bRow + (n << 10) + c0];
        }
        SCHED0();
        __builtin_amdgcn_s_setprio(1);
#pragma unroll
        for (int m = 0; m < 4; ++m)
#pragma unroll
            for (int n = 0; n < 4; ++n)
                acc[m][n] = __builtin_amdgcn_mfma_f32_16x16x32_f16(af1[m], bf1[n], acc[m][n], 0, 0, 0);
        __builtin_amdgcn_s_setprio(0);
        SCHED0();
    }

    const int cr = lq << 2;
    const int cc = lane & 15;
#pragma unroll
    for (int m = 0; m < 4; ++m) {
#pragma unroll
        for (int n = 0; n < 4; ++n) {
            const int ccol = bcol + wc + n * 16 + cc;
#pragma unroll
            for (int j = 0; j < 4; ++j) {
                const int crow = brow + wr + m * 16 + cr + j;
                float v = acc[m][n][j] + bias[ccol];
                const size_t o = (size_t)crow * N + ccol;
                if (EPI == 1) {
                    oSta[o] = (_Float16)v;
                    oS[o] = (_Float16)tanhf(v);
                } else {
                    Cout[o] = v;
                }
            }
        }
    }
}

// ================= small prep kernels =================
__global__ void cvt3(const float* __restrict__ s0, _Float16* __restrict__ d0, int n0,
                     const float* __restrict__ s1, _Float16* __restrict__ d1, int n1,
                     const float* __restrict__ s2, _Float16* __restrict__ d2) {
    int i = blockIdx.x * blockDim.x + threadIdx.x;
    const float* src; _Float16* dst; int k;
    if (i < n0)            { src = s0; dst = d0; k = i; }
    else if (i < n0 + n1)  { src = s1; dst = d1; k = i - n0; }
    else                   { src = s2; dst = d2; k = i - n0 - n1; }
    f32x4 v = *(const f32x4*)&src[(size_t)k * 4];
    half4 h;
    h[0] = (_Float16)v[0]; h[1] = (_Float16)v[1];
    h[2] = (_Float16)v[2]; h[3] = (_Float16)v[3];
    *(half4*)&dst[(size_t)k * 4] = h;
}

__global__ void transmul2(const float* __restrict__ W, const float* __restrict__ J,
                          const float* __restrict__ Mk,
                          _Float16* __restrict__ effT, _Float16* __restrict__ JmT) {
    __shared__ float tw[32][33];
    __shared__ float tj[32][33];
    const int bx = blockIdx.x * 32, by = blockIdx.y * 32;
    const int tx = threadIdx.x, ty0 = threadIdx.y;
#pragma unroll
    for (int r = 0; r < 4; ++r) {
        int ty = ty0 + r * 8;
        size_t idx = (size_t)(by + ty) * NN + bx + tx;
        float mv = Mk[idx];
        tw[ty][tx] = W[idx] * mv;
        tj[ty][tx] = J[idx] * mv;
    }
    __syncthreads();
#pragma unroll
    for (int r = 0; r < 4; ++r) {
        int ty = ty0 + r * 8;
        size_t o = (size_t)(bx + ty) * NN + by + tx;
        effT[o] = (_Float16)tw[tx][ty];
        JmT[o]  = (_Float16)tj[tx][ty];
    }
}

__global__ void tsc_kernel(const float* __restrict__ theta, float* __restrict__ Tsc) {
    int i = blockIdx.x * blockDim.x + threadIdx.x;
    if (i < NN) Tsc[i] = fabsf(sinf(2.0f * theta[i])) * 0.1f;
}

extern "C" void kernel_launch(void* const* d_in, const int* in_sizes, int n_in,
                              void* d_out, int out_size, void* d_ws, size_t ws_size,
                              hipStream_t stream) {
    const float* x       = (const float*)d_in[0];
    const float* W_in    = (const float*)d_in[1];
    const float* b_in    = (const float*)d_in[2];
    const float* weights = (const float*)d_in[3];
    const float* Jmat    = (const float*)d_in[4];
    const float* theta   = (const float*)d_in[5];
    const float* lam     = (const float*)d_in[6];
    const float* mask    = (const float*)d_in[7];
    const float* noise   = (const float*)d_in[8];
    const float* W_out   = (const float*)d_in[9];
    const float* b_out   = (const float*)d_in[10];
    float* out = (float*)d_out;

    char* w = (char*)d_ws;
    auto alloc = [&](size_t b) { char* p = w; w += (b + 255) & ~(size_t)255; return p; };
    _Float16* xh    = (_Float16*)alloc((size_t)TOKENS * IN_DIM * 2);
    _Float16* WinH  = (_Float16*)alloc((size_t)NN * IN_DIM * 2);
    _Float16* WoutH = (_Float16*)alloc((size_t)OUT_DIM * NN * 2);
    _Float16* effT  = (_Float16*)alloc((size_t)NN * NN * 2);
    _Float16* JmT   = (_Float16*)alloc((size_t)NN * NN * 2);
    _Float16* stA   = (_Float16*)alloc((size_t)TOKENS * NN * 2);
    _Float16* sA    = (_Float16*)alloc((size_t)TOKENS * NN * 2);
    _Float16* stB   = (_Float16*)alloc((size_t)TOKENS * NN * 2);
    _Float16* sB    = (_Float16*)alloc((size_t)TOKENS * NN * 2);
    float* Tsc      = (float*)alloc((size_t)NN * 4);

    const int n0 = TOKENS * IN_DIM / 4;
    const int n1 = NN * IN_DIM / 4;
    const int n2 = OUT_DIM * NN / 4;
    cvt3<<<(n0 + n1 + n2) / 256, 256, 0, stream>>>(x, xh, n0, W_in, WinH, n1, W_out, WoutH);
    transmul2<<<dim3(NN / 32, NN / 32), dim3(32, 8), 0, stream>>>(weights, Jmat, mask, effT, JmT);
    tsc_kernel<<<NN / 256, 256, 0, stream>>>(theta, Tsc);

    // state = x @ W_in.T + b_in
    pgemm<1><<<(TOKENS / 128) * (NN / 128), 256, 0, stream>>>(
        xh, WinH, nullptr, b_in, stA, sA, IN_DIM, NN, 4);

    for (int t = 0; t < TSTEPS; ++t) {
        fused_dual<<<256, 512, 0, stream>>>(
            stA, sA, effT, JmT, noise + (size_t)t * TOKENS * NN, Tsc, lam, stB, sB);
        _Float16* tmp;
        tmp = stA; stA = stB; stB = tmp;
        tmp = sA;  sA = sB;  sB = tmp;
    }

    // out = state @ W_out.T + b_out
    pgemm<2><<<(TOKENS / 128) * (OUT_DIM / 128), 256, 0, stream>>>(
        stA, WoutH, out, b_out, nullptr, nullptr, NN, OUT_DIM, 3);
}

// Round 14
// 333.390 us; speedup vs baseline: 1.3207x; 1.3207x over previous
//
#include <hip/hip_runtime.h>
#include <hip/hip_fp16.h>

#define TOKENS 4096
#define NN 2048
#define IN_DIM 1024
#define OUT_DIM 1024
#define TSTEPS 3

typedef _Float16 half8 __attribute__((ext_vector_type(8)));
typedef _Float16 half4 __attribute__((ext_vector_type(4)));
typedef float f32x4 __attribute__((ext_vector_type(4)));

__device__ __forceinline__ void gload_lds16(const void* g, void* l) {
    __builtin_amdgcn_global_load_lds(
        (const __attribute__((address_space(1))) unsigned*)g,
        (__attribute__((address_space(3))) unsigned*)l, 16, 0, 0);
}

#define LGKM(N) asm volatile("s_waitcnt lgkmcnt(" #N ")" ::: "memory")
#define VMCNT(N) asm volatile("s_waitcnt vmcnt(" #N ")" ::: "memory")
#define SCHED0() __builtin_amdgcn_sched_barrier(0)

// ================= pipelined dual GEMM (recurrent step) =================
// r12 kernel verbatim (best measured: 67.3 us, 0 bank conflicts, race-clean).
__global__ __launch_bounds__(512, 2)
void dual_gemm(const _Float16* __restrict__ A0g, const _Float16* __restrict__ B0g,
               _Float16* __restrict__ C0,
               const _Float16* __restrict__ A1g, const _Float16* __restrict__ B1g,
               _Float16* __restrict__ C1)
{
    __shared__ __align__(16) _Float16 lds[2 * 32768];   // 128 KiB
    const int tid  = threadIdx.x;
    const int wid  = tid >> 6;
    const int lane = tid & 63;

    const int raw  = blockIdx.x;
    const int widx = (raw & 7) * 32 + (raw >> 3);
    const int g    = widx >> 7;
    const int bid  = widx & 127;
    const int by = bid >> 3;
    const int bx = bid & 7;
    const _Float16* __restrict__ A = g ? A1g : A0g;
    const _Float16* __restrict__ B = g ? B1g : B0g;
    _Float16* __restrict__ C = g ? C1 : C0;
    const int brow = by << 8;
    const int bcol = bx << 8;

    const int sr = tid >> 3;
    const int sc = ((tid & 7) ^ (sr & 7)) << 3;
    const _Float16* gA = A + (size_t)(brow + sr) * NN + sc;
    const _Float16* gB = B + (size_t)(bcol + sr) * NN + sc;
    const int ldst = wid << 9;

    auto stA = [&](int T, int h) {
        _Float16* l = lds + (T & 1) * 32768 + h * 8192;
        const _Float16* p = gA + (size_t)(h << 7) * NN + (T << 6);
        gload_lds16(p,           l + ldst);
        gload_lds16(p + 64 * NN, l + 4096 + ldst);
    };
    auto stB = [&](int T, int h) {
        _Float16* l = lds + (T & 1) * 32768 + 16384 + h * 8192;
        const _Float16* p = gB + (size_t)(h << 7) * NN + (T << 6);
        gload_lds16(p,           l + ldst);
        gload_lds16(p + 64 * NN, l + 4096 + ldst);
    };

    const int wr = (wid >> 2) << 7;
    const int wc = (wid & 3) << 6;
    const int lr = lane & 15;
    const int lq = lane >> 4;
    const int x7 = lr & 7;
    const int c0 = (lq ^ x7) << 3;
    const int c1 = ((4 + lq) ^ x7) << 3;
    const int aRow = (wr + lr) << 6;
    const int bRow = 16384 + ((wc + lr) << 6);

    f32x4 acc[8][4];
#pragma unroll
    for (int m = 0; m < 8; ++m)
#pragma unroll
        for (int n = 0; n < 4; ++n) acc[m][n] = (f32x4){0.f, 0.f, 0.f, 0.f};

    half8 a0[8], a1[8], b0[4], b1[4];

    stA(0, 0); stA(0, 1); stB(0, 0); stB(0, 1);
    stA(1, 0); stA(1, 1); stB(1, 0); stB(1, 1);
    VMCNT(8);
    __builtin_amdgcn_s_barrier();
    asm volatile("" ::: "memory");

    for (int T = 0; T < 32; ++T) {
        const _Float16* lb = lds + (T & 1) * 32768;

#pragma unroll
        for (int m = 0; m < 4; ++m) a0[m] = *(const half8*)&lb[aRow + (m << 10) + c0];
#pragma unroll
        for (int n = 0; n < 4; ++n) b0[n] = *(const half8*)&lb[bRow + (n << 10) + c0];
#pragma unroll
        for (int m = 4; m < 8; ++m) a0[m] = *(const half8*)&lb[aRow + (m << 10) + c0];
#pragma unroll
        for (int m = 0; m < 4; ++m) a1[m] = *(const half8*)&lb[aRow + (m << 10) + c1];
#pragma unroll
        for (int n = 0; n < 4; ++n) b1[n] = *(const half8*)&lb[bRow + (n << 10) + c1];
#pragma unroll
        for (int m = 4; m < 8; ++m) a1[m] = *(const half8*)&lb[aRow + (m << 10) + c1];

        LGKM(15);
        SCHED0();
        __builtin_amdgcn_s_setprio(1);
#pragma unroll
        for (int m = 0; m < 4; ++m)
#pragma unroll
            for (int n = 0; n < 4; ++n)
                acc[m][n] = __builtin_amdgcn_mfma_f32_16x16x32_f16(a0[m], b0[n], acc[m][n], 0, 0, 0);
        __builtin_amdgcn_s_setprio(0);
        SCHED0();

        LGKM(12);
        SCHED0();
        __builtin_amdgcn_s_setprio(1);
#pragma unroll
        for (int m = 0; m < 4; ++m)
#pragma unroll
            for (int n = 0; n < 4; ++n)
                acc[m + 4][n] = __builtin_amdgcn_mfma_f32_16x16x32_f16(a0[m + 4], b0[n], acc[m + 4][n], 0, 0, 0);
        __builtin_amdgcn_s_setprio(0);
        SCHED0();

        LGKM(4);
        SCHED0();
        __builtin_amdgcn_s_setprio(1);
#pragma unroll
        for (int m = 0; m < 4; ++m)
#pragma unroll
            for (int n = 0; n < 4; ++n)
                acc[m][n] = __builtin_amdgcn_mfma_f32_16x16x32_f16(a1[m], b1[n], acc[m][n], 0, 0, 0);
        __builtin_amdgcn_s_setprio(0);
        SCHED0();

        LGKM(0);
        __builtin_amdgcn_s_barrier();
        if (T < 30) { stA(T + 2, 0); stA(T + 2, 1); stB(T + 2, 0); stB(T + 2, 1); }
        if (T < 30) { VMCNT(8); }
        else        { VMCNT(0); }
        __builtin_amdgcn_s_barrier();
        asm volatile("" ::: "memory");

        __builtin_amdgcn_s_setprio(1);
#pragma unroll
        for (int m = 0; m < 4; ++m)
#pragma unroll
            for (int n = 0; n < 4; ++n)
                acc[m + 4][n] = __builtin_amdgcn_mfma_f32_16x16x32_f16(a1[m + 4], b1[n], acc[m + 4][n], 0, 0, 0);
        __builtin_amdgcn_s_setprio(0);
        SCHED0();
    }

    const int cr = lq << 2;
    const int cc = lane & 15;
#pragma unroll
    for (int m = 0; m < 8; ++m) {
#pragma unroll
        for (int n = 0; n < 4; ++n) {
            const size_t o0 = (size_t)(brow + wr + m * 16 + cr) * NN
                            + (bcol + wc + n * 16 + cc);
#pragma unroll
            for (int j = 0; j < 4; ++j)
                C[o0 + (size_t)j * NN] = (_Float16)acc[m][n][j];
        }
    }
}

// ============ pipelined 128x128 GEMM (input/output projections) ============
template<int EPI>
__global__ __launch_bounds__(256, 2)
void pgemm(const _Float16* __restrict__ A, const _Float16* __restrict__ B,
           float* __restrict__ Cout, const float* __restrict__ bias,
           _Float16* __restrict__ oSta, _Float16* __restrict__ oS,
           int K, int N, int nbxLog2)
{
    __shared__ __align__(16) _Float16 lds[2 * 16384];   // 64 KiB
    const int tid  = threadIdx.x;
    const int wid  = tid >> 6;
    const int lane = tid & 63;

    const int raw  = blockIdx.x;
    const int cpx  = gridDim.x >> 3;
    const int widx = (raw & 7) * cpx + (raw >> 3);
    const int by = widx >> nbxLog2;
    const int bx = widx & ((1 << nbxLog2) - 1);
    const int brow = by << 7;
    const int bcol = bx << 7;

    const int sr = tid >> 3;
    const int sc = ((tid & 7) ^ (sr & 7)) << 3;
    const _Float16* gA = A + (size_t)(brow + sr) * K + sc;
    const _Float16* gB = B + (size_t)(bcol + sr) * K + sc;
    const int ldst = wid << 9;

    auto stA = [&](int T) {
        _Float16* l = lds + (T & 1) * 16384;
        const _Float16* p = gA + (T << 6);
#pragma unroll
        for (int r = 0; r < 4; ++r)
            gload_lds16(p + (size_t)(r * 32) * K, l + r * 2048 + ldst);
    };
    auto stB = [&](int T) {
        _Float16* l = lds + (T & 1) * 16384 + 8192;
        const _Float16* p = gB + (T << 6);
#pragma unroll
        for (int r = 0; r < 4; ++r)
            gload_lds16(p + (size_t)(r * 32) * K, l + r * 2048 + ldst);
    };

    const int wr = (wid >> 1) << 6;
    const int wc = (wid & 1) << 6;
    const int lr = lane & 15;
    const int lq = lane >> 4;
    const int x7 = lr & 7;
    const int c0 = (lq ^ x7) << 3;
    const int c1 = ((4 + lq) ^ x7) << 3;
    const int aRow = (wr + lr) << 6;
    const int bRow = 8192 + ((wc + lr) << 6);

    f32x4 acc[4][4];
#pragma unroll
    for (int m = 0; m < 4; ++m)
#pragma unroll
        for (int n = 0; n < 4; ++n) acc[m][n] = (f32x4){0.f, 0.f, 0.f, 0.f};

    half8 af0[4], af1[4], bf0[4], bf1[4];
    const int NT = K >> 6;

    stA(0); stB(0); stA(1); stB(1);
    VMCNT(8);
    __builtin_amdgcn_s_barrier();
    {
        const _Float16* lb = lds;
#pragma unroll
        for (int m = 0; m < 4; ++m) af0[m] = *(const half8*)&lb[aRow + (m << 10) + c0];
#pragma unroll
        for (int n = 0; n < 4; ++n) bf0[n] = *(const half8*)&lb[bRow + (n << 10) + c0];
    }

    for (int T = 0; T < NT; ++T) {
        const _Float16* lb = lds + (T & 1) * 16384;

#pragma unroll
        for (int m = 0; m < 4; ++m) af1[m] = *(const half8*)&lb[aRow + (m << 10) + c1];
#pragma unroll
        for (int n = 0; n < 4; ++n) bf1[n] = *(const half8*)&lb[bRow + (n << 10) + c1];
        LGKM(8);
        SCHED0();
        __builtin_amdgcn_s_setprio(1);
#pragma unroll
        for (int m = 0; m < 4; ++m)
#pragma unroll
            for (int n = 0; n < 4; ++n)
                acc[m][n] = __builtin_amdgcn_mfma_f32_16x16x32_f16(af0[m], bf0[n], acc[m][n], 0, 0, 0);
        __builtin_amdgcn_s_setprio(0);
        SCHED0();

        LGKM(0);
        __builtin_amdgcn_s_barrier();
        if (T < NT - 2) { stA(T + 2); stB(T + 2); VMCNT(8); }
        else if (T == NT - 2) { VMCNT(0); }
        __builtin_amdgcn_s_barrier();
        asm volatile("" ::: "memory");

        if (T < NT - 1) {
            const _Float16* ln = lds + ((T + 1) & 1) * 16384;
#pragma unroll
            for (int m = 0; m < 4; ++m) af0[m] = *(const half8*)&ln[aRow + (m << 10) + c0];
#pragma unroll
            for (int n = 0; n < 4; ++n) bf0[n] = *(const half8*)&ln[bRow + (n << 10) + c0];
        }
        SCHED0();
        __builtin_amdgcn_s_setprio(1);
#pragma unroll
        for (int m = 0; m < 4; ++m)
#pragma unroll
            for (int n = 0; n < 4; ++n)
                acc[m][n] = __builtin_amdgcn_mfma_f32_16x16x32_f16(af1[m], bf1[n], acc[m][n], 0, 0, 0);
        __builtin_amdgcn_s_setprio(0);
        SCHED0();
    }

    const int cr = lq << 2;
    const int cc = lane & 15;
#pragma unroll
    for (int m = 0; m < 4; ++m) {
#pragma unroll
        for (int n = 0; n < 4; ++n) {
            const int ccol = bcol + wc + n * 16 + cc;
#pragma unroll
            for (int j = 0; j < 4; ++j) {
                const int crow = brow + wr + m * 16 + cr + j;
                float v = acc[m][n][j] + bias[ccol];
                const size_t o = (size_t)crow * N + ccol;
                if (EPI == 1) {
                    oSta[o] = (_Float16)v;
                    oS[o] = (_Float16)tanhf(v);
                } else {
                    Cout[o] = v;
                }
            }
        }
    }
}

// ================= merged prep (cvt3 + transmul2 + tsc in ONE launch) =======
// blocks [0, 8192): f32->f16 casts of x, W_in, W_out (vec4 per thread)
// blocks [8192, 12288): masked transpose W*mask, J*mask -> f16 (32x32 tiles)
// blocks [12288, 12296): Tsc = |sin(2*theta)|*0.1
#define NB_CVT 8192
#define NB_TM  4096
__global__ __launch_bounds__(256)
void prep_all(const float* __restrict__ x, _Float16* __restrict__ xh, int n0,
              const float* __restrict__ W_in, _Float16* __restrict__ WinH, int n1,
              const float* __restrict__ W_out, _Float16* __restrict__ WoutH,
              const float* __restrict__ W, const float* __restrict__ J,
              const float* __restrict__ Mk,
              _Float16* __restrict__ effT, _Float16* __restrict__ JmT,
              const float* __restrict__ theta, float* __restrict__ Tsc)
{
    const int b = blockIdx.x;
    const int tid = threadIdx.x;
    if (b < NB_CVT) {
        const int i = b * 256 + tid;
        const float* src; _Float16* dst; int k;
        if (i < n0)           { src = x;     dst = xh;    k = i; }
        else if (i < n0 + n1) { src = W_in;  dst = WinH;  k = i - n0; }
        else                  { src = W_out; dst = WoutH; k = i - n0 - n1; }
        f32x4 v = *(const f32x4*)&src[(size_t)k * 4];
        half4 h;
        h[0] = (_Float16)v[0]; h[1] = (_Float16)v[1];
        h[2] = (_Float16)v[2]; h[3] = (_Float16)v[3];
        *(half4*)&dst[(size_t)k * 4] = h;
    } else if (b < NB_CVT + NB_TM) {
        __shared__ float tw[32][33];
        __shared__ float tj[32][33];
        const int bb = b - NB_CVT;
        const int bx = (bb & 63) * 32, by = (bb >> 6) * 32;
        const int tx = tid & 31, ty0 = tid >> 5;
#pragma unroll
        for (int r = 0; r < 4; ++r) {
            int ty = ty0 + r * 8;
            size_t idx = (size_t)(by + ty) * NN + bx + tx;
            float mv = Mk[idx];
            tw[ty][tx] = W[idx] * mv;
            tj[ty][tx] = J[idx] * mv;
        }
        __syncthreads();
#pragma unroll
        for (int r = 0; r < 4; ++r) {
            int ty = ty0 + r * 8;
            size_t o = (size_t)(bx + ty) * NN + by + tx;
            effT[o] = (_Float16)tw[tx][ty];
            JmT[o]  = (_Float16)tj[tx][ty];
        }
    } else {
        const int i = (b - NB_CVT - NB_TM) * 256 + tid;
        if (i < NN) Tsc[i] = fabsf(sinf(2.0f * theta[i])) * 0.1f;
    }
}

// ================= elementwise step =================
__global__ void step_kernel(const _Float16* __restrict__ signalH, const _Float16* __restrict__ sJH,
                            const float* __restrict__ noise, const float* __restrict__ Tsc,
                            const float* __restrict__ lamp,
                            _Float16* __restrict__ stateH, _Float16* __restrict__ sH) {
    const int i4 = blockIdx.x * blockDim.x + threadIdx.x;
    const float lam = lamp[0];
    const size_t base = (size_t)i4 * 4;
    half4 sg = *(const half4*)&signalH[base];
    half4 dj = *(const half4*)&sJH[base];
    f32x4 nz = *(const f32x4*)&noise[base];
    const int col4 = (int)(base & (NN - 1));
    f32x4 tv = *(const f32x4*)&Tsc[col4];
    half4 so = *(const half4*)&sH[base];
    half4 hs, hn;
#pragma unroll
    for (int j = 0; j < 4; ++j) {
        float s = (float)so[j];
        float arg = (float)sg[j] + lam * ((float)dj[j] * s) + nz[j] * tv[j];
        float st = tanhf(arg);
        hs[j] = (_Float16)st;
        hn[j] = (_Float16)tanhf(st);
    }
    *(half4*)&stateH[base] = hs;
    *(half4*)&sH[base] = hn;
}

extern "C" void kernel_launch(void* const* d_in, const int* in_sizes, int n_in,
                              void* d_out, int out_size, void* d_ws, size_t ws_size,
                              hipStream_t stream) {
    const float* x       = (const float*)d_in[0];
    const float* W_in    = (const float*)d_in[1];
    const float* b_in    = (const float*)d_in[2];
    const float* weights = (const float*)d_in[3];
    const float* Jmat    = (const float*)d_in[4];
    const float* theta   = (const float*)d_in[5];
    const float* lam     = (const float*)d_in[6];
    const float* mask    = (const float*)d_in[7];
    const float* noise   = (const float*)d_in[8];
    const float* W_out   = (const float*)d_in[9];
    const float* b_out   = (const float*)d_in[10];
    float* out = (float*)d_out;

    char* w = (char*)d_ws;
    auto alloc = [&](size_t b) { char* p = w; w += (b + 255) & ~(size_t)255; return p; };
    _Float16* xh      = (_Float16*)alloc((size_t)TOKENS * IN_DIM * 2);
    _Float16* WinH    = (_Float16*)alloc((size_t)NN * IN_DIM * 2);
    _Float16* WoutH   = (_Float16*)alloc((size_t)OUT_DIM * NN * 2);
    _Float16* effT    = (_Float16*)alloc((size_t)NN * NN * 2);
    _Float16* JmT     = (_Float16*)alloc((size_t)NN * NN * 2);
    _Float16* stateH  = (_Float16*)alloc((size_t)TOKENS * NN * 2);
    _Float16* sH      = (_Float16*)alloc((size_t)TOKENS * NN * 2);
    _Float16* signalH = (_Float16*)alloc((size_t)TOKENS * NN * 2);
    _Float16* sJH     = (_Float16*)alloc((size_t)TOKENS * NN * 2);
    float* Tsc        = (float*)alloc((size_t)NN * 4);

    const int n0 = TOKENS * IN_DIM / 4;
    const int n1 = NN * IN_DIM / 4;
    prep_all<<<NB_CVT + NB_TM + NN / 256, 256, 0, stream>>>(
        x, xh, n0, W_in, WinH, n1, W_out, WoutH,
        weights, Jmat, mask, effT, JmT, theta, Tsc);

    // state = x @ W_in.T + b_in
    pgemm<1><<<(TOKENS / 128) * (NN / 128), 256, 0, stream>>>(
        xh, WinH, nullptr, b_in, stateH, sH, IN_DIM, NN, 4);

    for (int t = 0; t < TSTEPS; ++t) {
        dual_gemm<<<256, 512, 0, stream>>>(stateH, effT, signalH, sH, JmT, sJH);
        step_kernel<<<TOKENS * NN / 4 / 256, 256, 0, stream>>>(
            signalH, sJH, noise + (size_t)t * TOKENS * NN, Tsc, lam, stateH, sH);
    }

    // out = state @ W_out.T + b_out
    pgemm<2><<<(TOKENS / 128) * (OUT_DIM / 128), 256, 0, stream>>>(
        stateH, WoutH, out, b_out, nullptr, nullptr, NN, OUT_DIM, 3);
}